// Round 1
// baseline (482.209 us; speedup 1.0000x reference)
//
#include <hip/hip_runtime.h>
#include <math.h>

#define B_ 32
#define T_ 256
#define H_ 128
#define KL_ 500
#define KS_ 10

// ---------------- K1: convolutions -> xf[B][T][6] ----------------
// grid (32, 6): blockIdx.y 0..2 = conv_l output channel, 3..5 = conv_s channel
__global__ void k_conv(const float* __restrict__ in1, const float* __restrict__ in2,
                       const float* __restrict__ wl, const float* __restrict__ bl,
                       const float* __restrict__ ws, const float* __restrict__ bs,
                       float* __restrict__ xf) {
    int b = blockIdx.x, oc = blockIdx.y;
    int t = threadIdx.x;  // 256 threads, one output timestep each
    __shared__ float s_in[755 * 3];
    __shared__ float s_w[3 * KL_];
    if (oc < 3) {
        int o = oc;
        for (int i = t; i < 755 * 3; i += 256) s_in[i] = in1[b * 755 * 3 + i];
        for (int i = t; i < 3 * KL_; i += 256) s_w[i] = wl[o * 3 * KL_ + i];
        __syncthreads();
        float acc = bl[o];
        for (int i = 0; i < 3; ++i) {
            const float* wrow = &s_w[i * KL_];
            #pragma unroll 4
            for (int k = 0; k < KL_; ++k)
                acc += s_in[(t + k) * 3 + i] * wrow[k];
        }
        xf[(b * T_ + t) * 6 + o] = acc;
    } else {
        int o = oc - 3;
        for (int i = t; i < 265 * 3; i += 256) s_in[i] = in2[b * 265 * 3 + i];
        for (int i = t; i < 3 * KS_; i += 256) s_w[i] = ws[o * 3 * KS_ + i];
        __syncthreads();
        float acc = bs[o];
        for (int i = 0; i < 3; ++i) {
            #pragma unroll
            for (int k = 0; k < KS_; ++k)
                acc += s_in[(t + k) * 3 + i] * s_w[i * KS_ + k];
        }
        xf[(b * T_ + t) * 6 + 3 + o] = acc;
    }
}

// ---------------- K1c: hb = h @ W_hh.T + b_h ; copy h to d_out[32:] ----------------
__global__ void k_hb(const float* __restrict__ h, const float* __restrict__ Whh,
                     const float* __restrict__ bh, float* __restrict__ hb,
                     float* __restrict__ dout) {
    int b = blockIdx.x, hh = threadIdx.x;  // 32 blocks x 128 threads
    __shared__ float hrow[128];
    hrow[hh] = h[b * 128 + hh];
    __syncthreads();
    float acc = bh[hh];
    #pragma unroll 4
    for (int k = 0; k < 128; ++k) acc += hrow[k] * Whh[hh * 128 + k];
    hb[b * 128 + hh] = acc;
    dout[32 + b * 128 + hh] = hrow[hh];
}

// ---------------- K2: out_t -> trv_all[t][b][k], lblT[t][h][b], outq ----------------
// grid 256 (one block per t), 256 threads
__global__ void k_feat(const float* __restrict__ xf, const float* __restrict__ in3,
                       const float* __restrict__ hb, const float* __restrict__ Wih,
                       const float* __restrict__ tk, const float* __restrict__ tv,
                       const float* __restrict__ tq,
                       float* __restrict__ trvA, float* __restrict__ lblT,
                       float* __restrict__ outq) {
    int t = blockIdx.x;
    int tid = threadIdx.x;
    __shared__ float out_s[B_ * H_];              // [b][h]
    __shared__ __align__(16) float tkc[16 * H_];
    __shared__ __align__(16) float tvc[16 * H_];
    __shared__ __align__(16) float tqc[16 * H_];

    for (int o = 0; o < 16; ++o) {
        int idx = o * 256 + tid;
        int b = idx >> 7, hh = idx & 127;
        const float* w = &Wih[hh * 9];
        const float* x6 = &xf[(b * T_ + t) * 6];
        const float* x3 = &in3[(b * T_ + t) * 3];
        float acc = hb[idx];
        acc += x6[0] * w[0] + x6[1] * w[1] + x6[2] * w[2]
             + x6[3] * w[3] + x6[4] * w[4] + x6[5] * w[5]
             + x3[0] * w[6] + x3[1] * w[7] + x3[2] * w[8];
        out_s[idx] = acc;
    }
    __syncthreads();

    float a_tr[16], a_lb[16], a_tq[16];
    #pragma unroll
    for (int o = 0; o < 16; ++o) { a_tr[o] = 0.f; a_lb[o] = 0.f; a_tq[o] = 0.f; }
    const bool last = (t == T_ - 1);

    for (int kc = 0; kc < 8; ++kc) {
        __syncthreads();  // protect reuse of staging buffers
        {
            const float4* s1 = (const float4*)(tk + kc * 2048);
            const float4* s2 = (const float4*)(tv + kc * 2048);
            float4* d1 = (float4*)tkc;
            float4* d2 = (float4*)tvc;
            d1[tid * 2]     = s1[tid * 2];
            d1[tid * 2 + 1] = s1[tid * 2 + 1];
            d2[tid * 2]     = s2[tid * 2];
            d2[tid * 2 + 1] = s2[tid * 2 + 1];
            if (last) {
                const float4* s3 = (const float4*)(tq + kc * 2048);
                float4* d3 = (float4*)tqc;
                d3[tid * 2]     = s3[tid * 2];
                d3[tid * 2 + 1] = s3[tid * 2 + 1];
            }
        }
        __syncthreads();
        for (int o = 0; o < 16; ++o) {
            int idx = o * 256 + tid;
            int b = idx >> 7, hh = idx & 127;
            const float* os = &out_s[b * 128 + kc * 16];
            #pragma unroll
            for (int k2 = 0; k2 < 16; ++k2) {
                float ov = os[k2];
                a_tr[o] += ov * tkc[k2 * 128 + hh];
                a_lb[o] += ov * tvc[k2 * 128 + hh];
                if (last) a_tq[o] += ov * tqc[k2 * 128 + hh];
            }
        }
    }
    for (int o = 0; o < 16; ++o) {
        int idx = o * 256 + tid;
        int b = idx >> 7, hh = idx & 127;
        trvA[t * 4096 + idx] = a_tr[o];
        lblT[t * 4096 + hh * 32 + b] = a_lb[o];
        if (last) outq[idx] = a_tq[o];
    }
}

// ---------------- K3: the Adam scan, one block per Wm row h ----------------
// 128 blocks x 256 threads. 2 barriers/step.
__global__ __launch_bounds__(256) void k_scan(
    const float* __restrict__ trvA, const float* __restrict__ lblT,
    const float* __restrict__ Wm0, const float* __restrict__ bm0,
    const float* __restrict__ outq, float* __restrict__ hi_ws) {
    const int h = blockIdx.x;
    const int tid = threadIdx.x;

    __shared__ __align__(16) float tb[2][B_][132];   // trv tile, padded rows (conflict-free f4)
    __shared__ float lbl_s[2][B_];
    __shared__ float g_s[B_];
    __shared__ __align__(16) float w_s[H_];
    __shared__ float bm_sh[1];

    const int b  = tid >> 3;            // phase A: batch row
    const int kg = (tid & 7) * 16;      // phase A: k-slice start
    const int k_own = tid >> 1;         // phase B/Adam: owned k (even tids)

    float wreg = 0.f, mW = 0.f, vW = 0.f;
    if ((tid & 1) == 0) { wreg = Wm0[h * 128 + k_own]; w_s[k_own] = wreg; }
    float bmreg = 0.f, mb = 0.f, vb = 0.f;
    if (tid == 0) { bmreg = bm0[h]; bm_sh[0] = bmreg; }

    // stage t=0
    {
        const float4* src = (const float4*)trvA;
        float4* dst = (float4*)&tb[0][b][kg];
        #pragma unroll
        for (int i = 0; i < 4; ++i) dst[i] = src[tid * 4 + i];
        if (tid < 32) lbl_s[0][tid] = lblT[h * 32 + tid];
    }
    __syncthreads();

    const float cgrad = 2.0f / 4096.0f;
    const float lr = 0.01f, B1 = 0.9f, B2 = 0.999f, EPS = 1e-8f;
    float pb1 = 1.f, pb2 = 1.f;

    for (int t = 0; t < T_; ++t) {
        const int cur = t & 1, nxt = cur ^ 1;

        // prefetch t+1 into registers (issue early, write late)
        float4 pf0, pf1, pf2, pf3;
        float lblpf = 0.f;
        if (t + 1 < T_) {
            const float4* src = (const float4*)(trvA + (size_t)(t + 1) * 4096);
            pf0 = src[tid * 4 + 0]; pf1 = src[tid * 4 + 1];
            pf2 = src[tid * 4 + 2]; pf3 = src[tid * 4 + 3];
            if (tid < 32) lblpf = lblT[(size_t)(t + 1) * 4096 + h * 32 + tid];
        }

        // ---- phase A: pred row, g ----
        float acc = 0.f;
        {
            const float4* t4 = (const float4*)&tb[cur][b][kg];
            const float4* w4 = (const float4*)&w_s[kg];
            #pragma unroll
            for (int j = 0; j < 4; ++j) {
                float4 a = t4[j], w = w4[j];
                acc += a.x * w.x + a.y * w.y + a.z * w.z + a.w * w.w;
            }
        }
        acc += __shfl_down(acc, 4, 8);
        acc += __shfl_down(acc, 2, 8);
        acc += __shfl_down(acc, 1, 8);
        if ((tid & 7) == 0)
            g_s[b] = cgrad * (acc + bm_sh[0] - lbl_s[cur][b]);
        __syncthreads();  // barrier 1: g visible

        pb1 *= B1; pb2 *= B2;
        const float rbc1 = 1.0f / (1.0f - pb1);
        const float rbc2 = 1.0f / (1.0f - pb2);

        // bias Adam on wave 0 (lanes 0..31)
        if (tid < 32) {
            float gv = g_s[tid];
            gv += __shfl_down(gv, 16, 32);
            gv += __shfl_down(gv, 8, 32);
            gv += __shfl_down(gv, 4, 32);
            gv += __shfl_down(gv, 2, 32);
            gv += __shfl_down(gv, 1, 32);
            if (tid == 0) {
                mb = B1 * mb + (1.f - B1) * gv;
                vb = B2 * vb + (1.f - B2) * gv * gv;
                bmreg -= lr * (mb * rbc1) / (sqrtf(vb * rbc2) + EPS);
                bm_sh[0] = bmreg;
            }
        }

        // ---- phase B: gW row + Adam ----
        {
            const int kk = tid >> 1;
            const int bh = (tid & 1) * 16;
            float accB = 0.f;
            #pragma unroll
            for (int bi = 0; bi < 16; ++bi)
                accB += g_s[bh + bi] * tb[cur][bh + bi][kk];
            accB += __shfl_down(accB, 1, 2);
            if ((tid & 1) == 0) {
                float gk = accB;
                mW = B1 * mW + (1.f - B1) * gk;
                vW = B2 * vW + (1.f - B2) * gk * gk;
                wreg -= lr * (mW * rbc1) / (sqrtf(vW * rbc2) + EPS);
                w_s[kk] = wreg;
            }
        }

        // write prefetched tile (safe: prior readers of tb[nxt] finished last step)
        if (t + 1 < T_) {
            float4* dst = (float4*)&tb[nxt][b][kg];
            dst[0] = pf0; dst[1] = pf1; dst[2] = pf2; dst[3] = pf3;
            if (tid < 32) lbl_s[nxt][tid] = lblpf;
        }
        __syncthreads();  // barrier 2: w_s/bm/next tile visible
    }

    // ---- epilogue: hi[:,h] = outq @ Wm_final[h,:] + bm_final ----
    {
        const float4* src = (const float4*)outq;
        float4* dst = (float4*)&tb[0][b][kg];
        #pragma unroll
        for (int i = 0; i < 4; ++i) dst[i] = src[tid * 4 + i];
    }
    __syncthreads();
    float acc = 0.f;
    {
        const float4* t4 = (const float4*)&tb[0][b][kg];
        const float4* w4 = (const float4*)&w_s[kg];
        #pragma unroll
        for (int j = 0; j < 4; ++j) {
            float4 a = t4[j], w = w4[j];
            acc += a.x * w.x + a.y * w.y + a.z * w.z + a.w * w.w;
        }
    }
    acc += __shfl_down(acc, 4, 8);
    acc += __shfl_down(acc, 2, 8);
    acc += __shfl_down(acc, 1, 8);
    if ((tid & 7) == 0) hi_ws[b * 128 + h] = acc + bm_sh[0];
}

// ---------------- K4: y = hi@W_ho.T + b_o ; out = y@out_W.T + out_b ----------------
__global__ void k_out(const float* __restrict__ hi, const float* __restrict__ Who,
                      const float* __restrict__ bo, const float* __restrict__ outW,
                      const float* __restrict__ outb, float* __restrict__ dout) {
    int b = blockIdx.x, hh = threadIdx.x;  // 32 blocks x 128 threads
    __shared__ float hrow[128];
    __shared__ float part[2];
    hrow[hh] = hi[b * 128 + hh];
    __syncthreads();
    float acc = bo[hh];
    #pragma unroll 4
    for (int k = 0; k < 128; ++k) acc += hrow[k] * Who[hh * 128 + k];
    float v = acc * outW[hh];
    v += __shfl_down(v, 32, 64);
    v += __shfl_down(v, 16, 64);
    v += __shfl_down(v, 8, 64);
    v += __shfl_down(v, 4, 64);
    v += __shfl_down(v, 2, 64);
    v += __shfl_down(v, 1, 64);
    if ((hh & 63) == 0) part[hh >> 6] = v;
    __syncthreads();
    if (hh == 0) dout[b] = part[0] + part[1] + outb[0];
}

extern "C" void kernel_launch(void* const* d_in, const int* in_sizes, int n_in,
                              void* d_out, int out_size, void* d_ws, size_t ws_size,
                              hipStream_t stream) {
    (void)in_sizes; (void)n_in; (void)out_size; (void)ws_size;
    const float* in1   = (const float*)d_in[0];   // [32,755,3]
    const float* in2   = (const float*)d_in[1];   // [32,265,3]
    const float* in3   = (const float*)d_in[2];   // [32,256,3]
    const float* h     = (const float*)d_in[3];   // [32,128]
    const float* Wih   = (const float*)d_in[4];   // [128,9]
    const float* Whh   = (const float*)d_in[5];   // [128,128]
    const float* bh    = (const float*)d_in[6];   // [128]
    const float* Who   = (const float*)d_in[7];   // [128,128]
    const float* bo    = (const float*)d_in[8];   // [128]
    const float* wl    = (const float*)d_in[9];   // [3,3,500]
    const float* bl    = (const float*)d_in[10];  // [3]
    const float* wsc   = (const float*)d_in[11];  // [3,3,10]
    const float* bsc   = (const float*)d_in[12];  // [3]
    const float* tk    = (const float*)d_in[13];  // [1,128,128]
    const float* tv    = (const float*)d_in[14];
    const float* tq    = (const float*)d_in[15];
    const float* Wm0   = (const float*)d_in[16];  // [128,128]
    const float* bm0   = (const float*)d_in[17];  // [128]
    const float* outW  = (const float*)d_in[18];  // [1,128]
    const float* outb  = (const float*)d_in[19];  // [1]
    float* out = (float*)d_out;

    float* wsf = (float*)d_ws;
    float* xf    = wsf;                      // 32*256*6   = 49152
    float* hb    = wsf + 49152;              // 4096
    float* trvA  = wsf + 53248;              // 256*32*128 = 1048576
    float* lblT  = wsf + 53248 + 1048576;    // 1048576
    float* outq  = wsf + 53248 + 2097152;    // 4096
    float* hi_ws = wsf + 53248 + 2101248;    // 4096

    k_conv<<<dim3(32, 6), 256, 0, stream>>>(in1, in2, wl, bl, wsc, bsc, xf);
    k_hb<<<32, 128, 0, stream>>>(h, Whh, bh, hb, out);
    k_feat<<<256, 256, 0, stream>>>(xf, in3, hb, Wih, tk, tv, tq, trvA, lblT, outq);
    k_scan<<<128, 256, 0, stream>>>(trvA, lblT, Wm0, bm0, outq, hi_ws);
    k_out<<<32, 128, 0, stream>>>(hi_ws, Who, bo, outW, outb, out);
}